// Round 15
// baseline (1366.814 us; speedup 1.0000x reference)
//
#include <hip/hip_runtime.h>

// MatchLSTM forward (Round 30): W-side fragment pre-pack for phase A.
//   R29 post-mortem: phase A 550us, still VALU-bound on in-loop W cvt_hilo
//   (4 W-cvts ~200 VALU per k0 vs 48 MFMA ~240cy), re-done by 32 x-blocks.
//   R30: pre-pack Wt + Wih_m(a_k half) + Wih_m(h half) as bf16 hi/lo
//   B-frags (same math as in-loop cvt -> BIT-IDENTICAL). Workspace dance:
//   packs live in pre_s (written LAST): WtP@pre_s[0], W3hP@pre_s[262144],
//   W3aP@pre_s[3407872]. Order: pack -> HYPOTHESIS (fusedA1 reads WtP/W3hP,
//   writes pre_t/pre_m_h) -> PREMISE per half {gather; g3pack_pw reads
//   W3aP -> G3; mfma_nt (fp32 Ws) -> pre_s, clobbering dead packs}.
//   Only Ws keeps the fp32 cvt path. Tripwire: absmax == 0.0009765625.
// phaseB (765us stable) + pack_wm + gather_fused: verbatim.

#define DEV static __device__ __forceinline__

DEV float fast_sigmoid(float x) { return 1.0f / (1.0f + __expf(-x)); }
DEV float fast_tanh(float x)    { return 1.0f - 2.0f / (__expf(2.0f * x) + 1.0f); }

DEV unsigned f2bf(float x) {
    unsigned v = __float_as_uint(x);
    return (v + 0x7FFFu + ((v >> 16) & 1u)) >> 16;
}
DEV float blo(unsigned u) { return __uint_as_float(u << 16); }

DEV float ntload(const float* p) { return __builtin_nontemporal_load(p); }

typedef __attribute__((ext_vector_type(8))) short bfrag;   // 8 bf16
typedef __attribute__((ext_vector_type(4))) float ffrag;   // 4 fp32 acc

// G3 block region (ushorts): 1536*64 data + 1024 pad = 99328 = 194KB
#define G3_BLK_S 99328

DEV void cvt_hilo(const float* v, bfrag& hi, bfrag& lo)
{
#pragma unroll
    for (int z = 0; z < 8; ++z) {
        unsigned h = f2bf(v[z]);
        hi[z] = (short)h;
        lo[z] = (short)f2bf(v[z] - __uint_as_float(h << 16));
    }
}

// ---------------------------------------------------------------------------
// pack_wfrag (R30): W fp32 -> bf16 hi/lo B-fragments.
//   frag uint4 idx = ((kc*NT + nt)*64 + lane)*2  {+0 hi, +1 lo}
//   blocks 0-127: Wt (NT=32, ldw 512); 128-511: Wih_m a_k-half (NT=96,
//   cols 0:512); 512-895: Wih_m h-half (cols 512:1024). Slice row srow =
//   nt*16+(lane&15); src row = gatebase(srow>>9) + (srow&511).
// ---------------------------------------------------------------------------
__global__ __launch_bounds__(256) void pack_wfrag_kernel(
    const float* __restrict__ Wt, const float* __restrict__ Wm3,
    uint4* __restrict__ WtP, uint4* __restrict__ W3aP, uint4* __restrict__ W3hP)
{
    const int bid = blockIdx.x;
    int i, NT, coff, ldw;
    const float* W;
    uint4* dst;
    if (bid < 128)      { i = bid * 256 + threadIdx.x;         NT = 32; W = Wt;  dst = WtP;  coff = 0;   ldw = 512;  }
    else if (bid < 512) { i = (bid - 128) * 256 + threadIdx.x; NT = 96; W = Wm3; dst = W3aP; coff = 0;   ldw = 1024; }
    else                { i = (bid - 512) * 256 + threadIdx.x; NT = 96; W = Wm3; dst = W3hP; coff = 512; ldw = 1024; }

    const int lane = i & 63;
    const int nt   = (i >> 6) % NT;
    const int kc   = (i >> 6) / NT;
    const int srow = nt * 16 + (lane & 15);
    int row = srow;
    if (NT == 96) {
        int gate = srow >> 9;
        row = (gate == 0 ? 0 : (gate == 1 ? 1024 : 1536)) + (srow & 511);
    }
    const int k = kc * 32 + ((lane >> 4) << 3) + coff;
    const float* wp = W + (size_t)row * ldw + k;
    float wvv[8] = {wp[0], wp[1], wp[2], wp[3], wp[4], wp[5], wp[6], wp[7]};
    bfrag whi, wlo;
    cvt_hilo(wvv, whi, wlo);
    *(bfrag*)(dst + (size_t)i * 2)     = whi;
    *(bfrag*)(dst + (size_t)i * 2 + 1) = wlo;
}

// ---------------------------------------------------------------------------
// gather_fused (validated R29): embed-gather 3-gate GEMM + gate math ->
// RhB bf16 hi/lo A-frags. Grid (128, 8), block 128.
// ---------------------------------------------------------------------------
__global__ __launch_bounds__(128, 2) void gather_fused_kernel(
    const float* __restrict__ embed, const int* __restrict__ gidx,
    const float* __restrict__ Wih,          // 2048 x 300
    const float* __restrict__ bih, const float* __restrict__ bhh,
    unsigned short* __restrict__ RhB)
{
    const int wv   = threadIdx.x >> 6;
    const int lane = threadIdx.x & 63;
    const int row  = lane & 15;
    const int quad = lane >> 4;
    const int m0 = blockIdx.x * 32 + wv * 16;
    const int j0 = blockIdx.y * 64;

    const int arow = gidx[m0 + row];

    ffrag acc[3][4];
#pragma unroll
    for (int g = 0; g < 3; ++g)
#pragma unroll
        for (int n = 0; n < 4; ++n)
#pragma unroll
            for (int r = 0; r < 4; ++r) acc[g][n][r] = 0.0f;

#pragma unroll 1
    for (int k0 = 0; k0 < 300; k0 += 32) {
        const bool tail = (k0 + 32 > 300);
        float av[8];
        if (!tail) {
            const float* ap = embed + (size_t)arow * 300 + k0 + quad * 8;
            float4 aA = *(const float4*)ap;
            float4 aB = *(const float4*)(ap + 4);
            av[0]=aA.x; av[1]=aA.y; av[2]=aA.z; av[3]=aA.w;
            av[4]=aB.x; av[5]=aB.y; av[6]=aB.z; av[7]=aB.w;
        } else {
#pragma unroll
            for (int z = 0; z < 8; ++z) {
                int kk = k0 + quad * 8 + z;
                av[z] = (kk < 300) ? embed[(size_t)arow * 300 + kk] : 0.0f;
            }
        }
        bfrag ahi, alo;
        cvt_hilo(av, ahi, alo);
#pragma unroll
        for (int g = 0; g < 3; ++g) {
            const int gbase = (g == 0) ? 0 : (g == 1 ? 1024 : 1536);
#pragma unroll
            for (int n = 0; n < 4; ++n) {
                const int wrow = gbase + j0 + n * 16 + row;
                float wvv[8];
                if (!tail) {
                    const float* wp = Wih + (size_t)wrow * 300 + k0 + quad * 8;
                    float4 wA = *(const float4*)wp;
                    float4 wB = *(const float4*)(wp + 4);
                    wvv[0]=wA.x; wvv[1]=wA.y; wvv[2]=wA.z; wvv[3]=wA.w;
                    wvv[4]=wB.x; wvv[5]=wB.y; wvv[6]=wB.z; wvv[7]=wB.w;
                } else {
#pragma unroll
                    for (int z = 0; z < 8; ++z) {
                        int kk = k0 + quad * 8 + z;
                        wvv[z] = (kk < 300) ? Wih[(size_t)wrow * 300 + kk] : 0.0f;
                    }
                }
                bfrag whi, wlo;
                cvt_hilo(wvv, whi, wlo);
                acc[g][n] = __builtin_amdgcn_mfma_f32_16x16x32_bf16(ahi, whi, acc[g][n], 0, 0, 0);
                acc[g][n] = __builtin_amdgcn_mfma_f32_16x16x32_bf16(alo, whi, acc[g][n], 0, 0, 0);
                acc[g][n] = __builtin_amdgcn_mfma_f32_16x16x32_bf16(ahi, wlo, acc[g][n], 0, 0, 0);
            }
        }
    }

#pragma unroll
    for (int n = 0; n < 4; ++n) {
        const int j = j0 + n * 16 + row;
        const float b0 = bih[j]        + bhh[j];
        const float b1 = bih[1024 + j] + bhh[1024 + j];
        const float b2 = bih[1536 + j] + bhh[1536 + j];
        const int kc     = j >> 5;
        const int lane_g = ((j >> 3) & 3) * 16;
        const int z      = j & 7;
#pragma unroll
        for (int r = 0; r < 4; ++r) {
            const int m = m0 + quad * 4 + r;
            float gi = acc[0][n][r] + b0;
            float gg = acc[1][n][r] + b1;
            float go = acc[2][n][r] + b2;
            float cc = fast_sigmoid(gi) * fast_tanh(gg);
            float hv = fast_sigmoid(go) * fast_tanh(cc);
            size_t idx = ((size_t)(kc * 256 + (m >> 4)) * 64
                          + lane_g + (m & 15)) * 16 + z;
            unsigned hb = f2bf(hv);
            RhB[idx]     = (unsigned short)hb;
            RhB[idx + 8] = (unsigned short)f2bf(hv - blo(hb));
        }
    }
}

// ---------------------------------------------------------------------------
// fusedA1 (R30): hypothesis side, PACKED W. y<8: Wt-nt -> pre_t;
// y>=8: Wih_m h-half 3-gate -> pre_m_h + bias. A from RhB.
// ---------------------------------------------------------------------------
__global__ __launch_bounds__(128, 2) void fusedA1_kernel(
    const uint4* __restrict__ AB,
    const uint4* __restrict__ WtP, const uint4* __restrict__ W3hP,
    const float* __restrict__ bias1, const float* __restrict__ bias2,
    float* __restrict__ outNT, float* __restrict__ outMH)
{
    const int wv   = threadIdx.x >> 6;
    const int lane = threadIdx.x & 63;
    const int row  = lane & 15;
    const int quad = lane >> 4;
    const int m0   = blockIdx.x * 128 + wv * 64;
    const int mt0  = m0 >> 4;
    const int yy   = blockIdx.y;
    const bool isNT = (yy < 8);

    int gate = 0, j0 = 0, gbase = 0, NTs, ntb;
    const uint4* WP;
    if (isNT) { WP = WtP; NTs = 32; ntb = yy * 4; }
    else {
        gate  = (yy - 8) >> 3;
        j0    = ((yy - 8) & 7) * 64;
        gbase = (gate == 0) ? 0 : (gate == 1 ? 1024 : 1536);
        WP = W3hP; NTs = 96; ntb = gate * 32 + ((yy - 8) & 7) * 4;
    }

    ffrag acc[4][4];
#pragma unroll
    for (int mt = 0; mt < 4; ++mt)
#pragma unroll
        for (int n = 0; n < 4; ++n)
#pragma unroll
            for (int r = 0; r < 4; ++r) acc[mt][n][r] = 0.0f;

#pragma unroll 1
    for (int k0 = 0; k0 < 512; k0 += 32) {
        const int kc = k0 >> 5;
        bfrag ahi[4], alo[4];
#pragma unroll
        for (int mt = 0; mt < 4; ++mt) {
            const uint4* ap = AB + ((size_t)(kc * 256 + mt0 + mt) * 64 + lane) * 2;
            ahi[mt] = *(const bfrag*)(ap);
            alo[mt] = *(const bfrag*)(ap + 1);
        }
#pragma unroll
        for (int n = 0; n < 4; ++n) {
            const uint4* wf = WP + ((size_t)(kc * NTs + ntb + n) * 64 + lane) * 2;
            bfrag whi = *(const bfrag*)(wf);
            bfrag wlo = *(const bfrag*)(wf + 1);
#pragma unroll
            for (int mt = 0; mt < 4; ++mt) {
                acc[mt][n] = __builtin_amdgcn_mfma_f32_16x16x32_bf16(ahi[mt], whi, acc[mt][n], 0, 0, 0);
                acc[mt][n] = __builtin_amdgcn_mfma_f32_16x16x32_bf16(alo[mt], whi, acc[mt][n], 0, 0, 0);
                acc[mt][n] = __builtin_amdgcn_mfma_f32_16x16x32_bf16(ahi[mt], wlo, acc[mt][n], 0, 0, 0);
            }
        }
    }

    if (isNT) {
#pragma unroll
        for (int mt = 0; mt < 4; ++mt)
#pragma unroll
            for (int n = 0; n < 4; ++n)
#pragma unroll
                for (int r = 0; r < 4; ++r)
                    outNT[(size_t)(m0 + mt * 16 + quad * 4 + r) * 512
                          + yy * 64 + n * 16 + row] = acc[mt][n][r];
    } else {
#pragma unroll
        for (int n = 0; n < 4; ++n) {
            const int j = j0 + n * 16 + row;
            const float bb = bias1[gbase + j] + bias2[gbase + j];
#pragma unroll
            for (int mt = 0; mt < 4; ++mt)
#pragma unroll
                for (int r = 0; r < 4; ++r) {
                    const int m = m0 + mt * 16 + quad * 4 + r;
                    outMH[((size_t)m * 3 + gate) * 512 + j] = acc[mt][n][r] + bb;
                }
        }
    }
}

// ---------------------------------------------------------------------------
// g3pack_pw (R30): premise 3-gate GEMM, PACKED W (a_k half) -> G3 t-major.
// Grid (32, 24).
// ---------------------------------------------------------------------------
__global__ __launch_bounds__(128, 2) void g3pack_pw_kernel(
    const uint4* __restrict__ AB, const uint4* __restrict__ W3aP,
    unsigned short* __restrict__ G3s, int mbase)
{
    const int wv   = threadIdx.x >> 6;
    const int lane = threadIdx.x & 63;
    const int row  = lane & 15;
    const int quad = lane >> 4;
    const int m0   = blockIdx.x * 128 + wv * 64;
    const int mt0  = m0 >> 4;
    const int gate = blockIdx.y >> 3;
    const int j0   = (blockIdx.y & 7) * 64;
    const int ntb  = gate * 32 + (blockIdx.y & 7) * 4;

    ffrag acc[4][4];
#pragma unroll
    for (int mt = 0; mt < 4; ++mt)
#pragma unroll
        for (int n = 0; n < 4; ++n)
#pragma unroll
            for (int r = 0; r < 4; ++r) acc[mt][n][r] = 0.0f;

#pragma unroll 1
    for (int k0 = 0; k0 < 512; k0 += 32) {
        const int kc = k0 >> 5;
        bfrag ahi[4], alo[4];
#pragma unroll
        for (int mt = 0; mt < 4; ++mt) {
            const uint4* ap = AB + ((size_t)(kc * 256 + mt0 + mt) * 64 + lane) * 2;
            ahi[mt] = *(const bfrag*)(ap);
            alo[mt] = *(const bfrag*)(ap + 1);
        }
#pragma unroll
        for (int n = 0; n < 4; ++n) {
            const uint4* wf = W3aP + ((size_t)(kc * 96 + ntb + n) * 64 + lane) * 2;
            bfrag whi = *(const bfrag*)(wf);
            bfrag wlo = *(const bfrag*)(wf + 1);
#pragma unroll
            for (int mt = 0; mt < 4; ++mt) {
                acc[mt][n] = __builtin_amdgcn_mfma_f32_16x16x32_bf16(ahi[mt], whi, acc[mt][n], 0, 0, 0);
                acc[mt][n] = __builtin_amdgcn_mfma_f32_16x16x32_bf16(alo[mt], whi, acc[mt][n], 0, 0, 0);
                acc[mt][n] = __builtin_amdgcn_mfma_f32_16x16x32_bf16(ahi[mt], wlo, acc[mt][n], 0, 0, 0);
            }
        }
    }
#pragma unroll
    for (int n = 0; n < 4; ++n) {
        const int j = j0 + n * 16 + row;
#pragma unroll
        for (int mt = 0; mt < 4; ++mt)
#pragma unroll
            for (int r = 0; r < 4; ++r) {
                const int mg = mbase + m0 + mt * 16 + quad * 4 + r;
                const int t = mg >> 7, b = mg & 127;
                size_t idx = (size_t)b * G3_BLK_S
                           + ((size_t)(gate * 512 + j)) * 64 + t;
                G3s[idx] = (unsigned short)f2bf(acc[mt][n][r]);
            }
    }
}

// ---------------------------------------------------------------------------
// MFMA GEMM (validated R28): premise nt, fp32 Ws. Grid (32, 8).
// ---------------------------------------------------------------------------
__global__ __launch_bounds__(128, 2) void mfma_nt_kernel(
    const uint4* __restrict__ AB, const float* __restrict__ W,
    float* __restrict__ C)
{
    const int wv   = threadIdx.x >> 6;
    const int lane = threadIdx.x & 63;
    const int row  = lane & 15;
    const int quad = lane >> 4;
    const int m0 = blockIdx.x * 128 + wv * 64;
    const int n0 = blockIdx.y * 64;
    const int mt0 = m0 >> 4;

    ffrag acc[4][4];
#pragma unroll
    for (int mt = 0; mt < 4; ++mt)
#pragma unroll
        for (int n = 0; n < 4; ++n)
#pragma unroll
            for (int r = 0; r < 4; ++r) acc[mt][n][r] = 0.0f;

#pragma unroll 1
    for (int k0 = 0; k0 < 512; k0 += 32) {
        const int kc = k0 >> 5;
        bfrag ahi[4], alo[4];
#pragma unroll
        for (int mt = 0; mt < 4; ++mt) {
            const uint4* ap = AB + ((size_t)(kc * 256 + mt0 + mt) * 64 + lane) * 2;
            ahi[mt] = *(const bfrag*)(ap);
            alo[mt] = *(const bfrag*)(ap + 1);
        }
#pragma unroll
        for (int n = 0; n < 4; ++n) {
            const float* wp = W + (size_t)(n0 + n * 16 + row) * 512 + k0 + quad * 8;
            float4 wA = *(const float4*)wp;
            float4 wB = *(const float4*)(wp + 4);
            float wvv[8] = {wA.x, wA.y, wA.z, wA.w, wB.x, wB.y, wB.z, wB.w};
            bfrag whi, wlo;
            cvt_hilo(wvv, whi, wlo);
#pragma unroll
            for (int mt = 0; mt < 4; ++mt) {
                acc[mt][n] = __builtin_amdgcn_mfma_f32_16x16x32_bf16(ahi[mt], whi, acc[mt][n], 0, 0, 0);
                acc[mt][n] = __builtin_amdgcn_mfma_f32_16x16x32_bf16(alo[mt], whi, acc[mt][n], 0, 0, 0);
                acc[mt][n] = __builtin_amdgcn_mfma_f32_16x16x32_bf16(ahi[mt], wlo, acc[mt][n], 0, 0, 0);
            }
        }
    }
#pragma unroll
    for (int mt = 0; mt < 4; ++mt)
#pragma unroll
        for (int n = 0; n < 4; ++n)
#pragma unroll
            for (int r = 0; r < 4; ++r)
                C[(size_t)(m0 + mt * 16 + quad * 4 + r) * 512 + n0 + n * 16 + row]
                    = acc[mt][n][r];
}

// ---------------------------------------------------------------------------
// Wm pack (validated R19): [kc][nt][lane] tile-interleaved.
// ---------------------------------------------------------------------------
__global__ __launch_bounds__(256) void pack_wm_kernel(
    const float* __restrict__ Wm, unsigned* __restrict__ WmB)
{
    int i = blockIdx.x * 256 + threadIdx.x;           // 0 .. 131071
    int u = i & 3, lane = (i >> 2) & 63;
    int nt = (i >> 8) & 31, kc = i >> 13;
    int row = nt * 16 + (lane & 15);
    int k = kc * 32 + ((lane >> 4) << 3) + u * 2;
    unsigned lo = f2bf(Wm[(size_t)row * 512 + k]);
    unsigned hi = f2bf(Wm[(size_t)row * 512 + k + 1]);
    WmB[i] = lo | (hi << 16);
}

// ---------------------------------------------------------------------------
// Phase B (R25 verbatim): GEMV1 K-split + MFMA G3-sum (t-major).
// ---------------------------------------------------------------------------
__global__ __launch_bounds__(1024) void phaseB_kernel(
    const float* __restrict__ pre_s, const float* __restrict__ pre_t,
    const float* __restrict__ pre_m_h,
    const unsigned* __restrict__ WmB, const unsigned short* __restrict__ G3s,
    const float* __restrict__ w_e,
    const float* __restrict__ fc_w,  const float* __restrict__ fc_b,
    float* __restrict__ out)
{
    extern __shared__ __align__(16) float psL[];      // 64*512 fp32 = 128KB
    __shared__ __align__(16) float hm[512];
    __shared__ __align__(16) float base[512];
    __shared__ __align__(16) float wesh[512];
    __shared__ __align__(16) float sc[64];
    __shared__ __align__(16) float red[2 * 512];
    __shared__ __align__(16) float gates3[1536];
    __shared__ __align__(16) unsigned short hmh[512];
    __shared__ __align__(16) unsigned short hml[512];
    __shared__ __align__(16) unsigned short sch[64];
    __shared__ __align__(16) unsigned short scl[64];

    const int b    = blockIdx.x;
    const int tid  = threadIdx.x;
    const int wv   = tid >> 6;
    const int lane = tid & 63;
    const int col  = lane & 15;
    const int quad = lane >> 4;

    if (tid < 512) {
        wesh[tid] = w_e[tid];
        hm[tid] = 0.0f; hmh[tid] = 0; hml[tid] = 0;
    }
    for (int i = tid; i < 32768; i += 1024) {
        int t = i >> 9, h = i & 511;
        psL[i] = ntload(&pre_s[((size_t)t * 128 + b) * 512 + h]);
    }
    __syncthreads();

    for (int k = 0; k < 64; ++k) {
        // ---- GEMV1 (K-split): partials for base = Wm . hm
        {
            const int kh2 = wv >> 3;
            const int tp  = (wv & 7) * 4;
            ffrag a0 = {0.0f,0.0f,0.0f,0.0f}, a1 = {0.0f,0.0f,0.0f,0.0f};
            ffrag a2 = {0.0f,0.0f,0.0f,0.0f}, a3 = {0.0f,0.0f,0.0f,0.0f};
            const uint4* wp = (const uint4*)WmB
                            + ((size_t)(kh2 * 8) * 32 + tp) * 64 + lane;
            const unsigned short* ab = ((lane & 8) == 0) ? hmh : hml;
#pragma unroll 1
            for (int kc = 0; kc < 8; ++kc) {
                bfrag a  = *(const bfrag*)&ab[(kh2 * 8 + kc) * 32 + quad * 8];
                bfrag w0 = *(const bfrag*)(wp);
                bfrag w1 = *(const bfrag*)(wp + 64);
                bfrag w2 = *(const bfrag*)(wp + 128);
                bfrag w3 = *(const bfrag*)(wp + 192);
                a0 = __builtin_amdgcn_mfma_f32_16x16x32_bf16(a, w0, a0, 0, 0, 0);
                a1 = __builtin_amdgcn_mfma_f32_16x16x32_bf16(a, w1, a1, 0, 0, 0);
                a2 = __builtin_amdgcn_mfma_f32_16x16x32_bf16(a, w2, a2, 0, 0, 0);
                a3 = __builtin_amdgcn_mfma_f32_16x16x32_bf16(a, w3, a3, 0, 0, 0);
                wp += 2048;
            }
            float s0 = a0[0] + __shfl_xor(a0[0], 32);
            float s1 = a1[0] + __shfl_xor(a1[0], 32);
            float s2 = a2[0] + __shfl_xor(a2[0], 32);
            float s3 = a3[0] + __shfl_xor(a3[0], 32);
            if (lane < 16) {
                float* rr = &red[kh2 * 512];
                rr[(tp + 0) * 16 + lane] = s0;
                rr[(tp + 1) * 16 + lane] = s1;
                rr[(tp + 2) * 16 + lane] = s2;
                rr[(tp + 3) * 16 + lane] = s3;
            }
        }
        __syncthreads();
        if (tid < 512)
            base[tid] = red[tid] + red[512 + tid]
                      + ntload(&pre_t[((size_t)k * 128 + b) * 512 + tid]);
        __syncthreads();

        // ---- attention scores: e[t] = w_e . tanh(psL[t] + base)  (all LDS)
#pragma unroll
        for (int tt = 0; tt < 4; ++tt) {
            int t = wv * 4 + tt;
            const float* ps = &psL[t * 512];
            float p = 0.0f;
#pragma unroll
            for (int u = 0; u < 8; ++u) {
                int h = lane + 64 * u;
                p += wesh[h] * fast_tanh(ps[h] + base[h]);
            }
#pragma unroll
            for (int off = 32; off; off >>= 1) p += __shfl_xor(p, off);
            if (lane == 0) sc[t] = p;
        }
        __syncthreads();

        // ---- softmax (+ bf16 hi/lo pack of alpha)
        if (wv == 0) {
            float s = sc[lane], mx = s;
#pragma unroll
            for (int off = 32; off; off >>= 1) mx = fmaxf(mx, __shfl_xor(mx, off));
            float e = __expf(s - mx), sum = e;
#pragma unroll
            for (int off = 32; off; off >>= 1) sum += __shfl_xor(sum, off);
            float a = e / sum;
            unsigned hb = f2bf(a);
            sch[lane] = (unsigned short)hb;
            scl[lane] = (unsigned short)f2bf(a - blo(hb));
        }
        __syncthreads();

        // ---- gates = sum_t alpha_t * G3T[b][:,t]  via MFMA (K=64)
        {
            const unsigned short* ab = ((lane & 8) == 0) ? sch : scl;
            bfrag aA = *(const bfrag*)&ab[quad * 8];
            bfrag aB = *(const bfrag*)&ab[32 + quad * 8];
            const unsigned short* gp = G3s + (size_t)b * G3_BLK_S
                                     + ((size_t)(wv * 96) + col) * 64 + quad * 8;
            ffrag g[6];
#pragma unroll
            for (int t6 = 0; t6 < 6; ++t6) {
                g[t6][0] = 0.0f; g[t6][1] = 0.0f; g[t6][2] = 0.0f; g[t6][3] = 0.0f;
            }
#pragma unroll
            for (int t6 = 0; t6 < 6; ++t6) {
                bfrag w0 = *(const bfrag*)(gp + t6 * 1024);
                g[t6] = __builtin_amdgcn_mfma_f32_16x16x32_bf16(aA, w0, g[t6], 0, 0, 0);
            }
#pragma unroll
            for (int t6 = 0; t6 < 6; ++t6) {
                bfrag w1 = *(const bfrag*)(gp + t6 * 1024 + 32);
                g[t6] = __builtin_amdgcn_mfma_f32_16x16x32_bf16(aB, w1, g[t6], 0, 0, 0);
            }
#pragma unroll
            for (int t6 = 0; t6 < 6; ++t6) {
                float s = g[t6][0] + __shfl_xor(g[t6][0], 32);
                if (lane < 16) gates3[(wv * 6 + t6) * 16 + lane] = s;
            }
        }
        __syncthreads();

        // ---- gate math -> hm (+ hi/lo pack for next step's GEMV1)
        if (tid < 512) {
            const size_t m = (size_t)k * 128 + b;
            float gi = gates3[tid]        + ntload(&pre_m_h[(m * 3 + 0) * 512 + tid]);
            float gg = gates3[512 + tid]  + ntload(&pre_m_h[(m * 3 + 1) * 512 + tid]);
            float go = gates3[1024 + tid] + ntload(&pre_m_h[(m * 3 + 2) * 512 + tid]);
            float cc = fast_sigmoid(gi) * fast_tanh(gg);
            float hv = fast_sigmoid(go) * fast_tanh(cc);
            hm[tid] = hv;
            unsigned hb = f2bf(hv);
            hmh[tid] = (unsigned short)hb;
            hml[tid] = (unsigned short)f2bf(hv - blo(hb));
        }
        __syncthreads();
    }

    if (wv < 3) {
        float p = 0.0f;
#pragma unroll
        for (int u = 0; u < 8; ++u) {
            int h = lane + 64 * u;
            p += hm[h] * fc_w[wv * 512 + h];
        }
#pragma unroll
        for (int off = 32; off; off >>= 1) p += __shfl_xor(p, off);
        if (lane == 0) out[b * 3 + wv] = p + fc_b[wv];
    }
}

extern "C" void kernel_launch(void* const* d_in, const int* in_sizes, int n_in,
                              void* d_out, int out_size, void* d_ws, size_t ws_size,
                              hipStream_t stream)
{
    (void)in_sizes; (void)n_in; (void)out_size;
    const int*   premise    = (const int*)d_in[0];
    const int*   hypothesis = (const int*)d_in[2];
    const float* embed  = (const float*)d_in[4];
    const float* w_e    = (const float*)d_in[5];
    const float* Ws     = (const float*)d_in[6];
    const float* Wt     = (const float*)d_in[7];
    const float* Wm     = (const float*)d_in[8];
    const float* Wih_p  = (const float*)d_in[9];
    const float* bih_p  = (const float*)d_in[10];
    const float* bhh_p  = (const float*)d_in[11];
    const float* Wih_h  = (const float*)d_in[12];
    const float* bih_h  = (const float*)d_in[13];
    const float* bhh_h  = (const float*)d_in[14];
    const float* Wih_m  = (const float*)d_in[15];
    const float* bih_m  = (const float*)d_in[16];
    const float* bhh_m  = (const float*)d_in[17];
    const float* fc_w   = (const float*)d_in[18];
    const float* fc_b   = (const float*)d_in[19];

    // Workspace layout (floats), total 29,425,664 <= guard 29,556,736:
    //   RhB     @ 0         : 2,097,152  (bf16 hi/lo A-frags; WmB aliases)
    //   pre_s   @ 2,097,152 : 4,194,304  (W packs live here until clobbered:
    //       WtP @ +0 (262,144), W3hP @ +262,144 (786,432),
    //       W3aP @ +3,407,872 (786,432, ends exactly at region end))
    //   pre_t   @ 6,291,456 : 4,194,304
    //   pre_m_h @10,485,760 :12,582,912
    //   G3      @23,068,672 : 6,356,992  (bf16 t-major, 194KB/block padded)
    float* ws      = (float*)d_ws;
    unsigned short* RhB = (unsigned short*)ws;
    const uint4* RhB4   = (const uint4*)ws;
    float* pre_s   = ws + 2097152;
    float* pre_t   = ws + 6291456;
    float* pre_m_h = ws + 10485760;
    unsigned short* G3s = (unsigned short*)(ws + 23068672);
    unsigned* WmB  = (unsigned*)ws;           // aliases RhB after last reader
    uint4* WtP  = (uint4*)(pre_s);
    uint4* W3hP = (uint4*)(pre_s + 262144);
    uint4* W3aP = (uint4*)(pre_s + 3407872);
    float* outp    = (float*)d_out;
    if (ws_size < (size_t)29556736 * 4) return;

    dim3 blk2(128);
    dim3 blk(256);

    // ---- W fragment packs (into pre_s region, clobbered later by design)
    pack_wfrag_kernel<<<896, blk, 0, stream>>>(Wt, Wih_m, WtP, W3aP, W3hP);

    // ---- HYPOTHESIS first: RhB -> {pre_t(half), pre_m_h(half)} (packed W)
    for (int h = 0; h < 2; ++h) {
        gather_fused_kernel<<<dim3(128, 8), blk2, 0, stream>>>(
            embed, hypothesis + h * 4096, Wih_h, bih_h, bhh_h, RhB);
        fusedA1_kernel<<<dim3(32, 32), blk2, 0, stream>>>(
            RhB4, WtP, W3hP, bih_m, bhh_m,
            pre_t + (size_t)h * 2097152, pre_m_h + (size_t)h * 6291456);
    }
    // ---- PREMISE: RhB -> G3(half) [packed W3a], then pre_s(half) [fp32 Ws]
    //      (nt runs AFTER g3pack each half; nt(h) clobbers dead packs only)
    for (int h = 0; h < 2; ++h) {
        gather_fused_kernel<<<dim3(128, 8), blk2, 0, stream>>>(
            embed, premise + h * 4096, Wih_p, bih_p, bhh_p, RhB);
        g3pack_pw_kernel<<<dim3(32, 24), blk2, 0, stream>>>(
            RhB4, W3aP, G3s, h * 4096);
        mfma_nt_kernel<<<dim3(32, 8), blk2, 0, stream>>>(
            RhB4, Ws, pre_s + (size_t)h * 2097152);
    }

    // ---- Wm pack (after RhB's last reader; output aliases RhB)
    pack_wm_kernel<<<512, blk, 0, stream>>>(Wm, WmB);

    // ---- Phase B (128KB dynamic LDS for pre_s cache)
    static int attr_done = 0;
    if (!attr_done) {
        hipFuncSetAttribute((const void*)phaseB_kernel,
                            hipFuncAttributeMaxDynamicSharedMemorySize, 131072);
        attr_done = 1;
    }
    phaseB_kernel<<<dim3(128), dim3(1024), 131072, stream>>>(
        pre_s, pre_t, pre_m_h, WmB, G3s, w_e, fc_w, fc_b, outp);
}